// Round 11
// baseline (252.872 us; speedup 1.0000x reference)
//
#include <hip/hip_runtime.h>

#define NEG_SLOPE 0.2f
#define GAT_EPS 1e-16f

__device__ __forceinline__ float leaky(float e){ return e > 0.f ? e : NEG_SLOPE * e; }

// pack two fp32 into bf16x2 (round-to-nearest-even), low = a, high = b
__device__ __forceinline__ unsigned bf2(float a, float b){
  unsigned ua = __float_as_uint(a); ua += 0x7FFFu + ((ua >> 16) & 1u);
  unsigned ub = __float_as_uint(b); ub += 0x7FFFu + ((ub >> 16) & 1u);
  return (ua >> 16) | (ub & 0xFFFF0000u);
}
__device__ __forceinline__ float bflo(unsigned v){ return __uint_as_float(v << 16); }
__device__ __forceinline__ float bfhi(unsigned v){ return __uint_as_float(v & 0xFFFF0000u); }

// ------- GEMM1: 64x64 tile, 4x4 register blocking; bf16 h1 + alpha dots -------
__global__ __launch_bounds__(256) void k_gemm1(const float* __restrict__ x,
                                               const float* __restrict__ W,
                                               const float* __restrict__ a_src,
                                               const float* __restrict__ a_dst,
                                               unsigned* __restrict__ h1b,
                                               float* __restrict__ as1,
                                               float* __restrict__ ad1, int N){
  __shared__ float Ws[128*64];   // [k][c], 32 KB
  __shared__ float xs[64*20];    // [row][k-chunk16] pad->20, 5 KB
  const int t = threadIdx.x;
  const int n0 = blockIdx.x * 64;
  for (int i = t; i < 128*64/4; i += 256) ((float4*)Ws)[i] = ((const float4*)W)[i];
  const int ct = t & 15;
  const int rt = t >> 4;
  const int lr = t >> 2;
  const int lq = t & 3;
  const bool rok = (n0 + lr) < N;
  const float* xrow = x + (size_t)(n0 + lr)*128 + lq*4;
  float acc[4][4];
#pragma unroll
  for (int i = 0; i < 4; i++)
#pragma unroll
    for (int j = 0; j < 4; j++) acc[i][j] = 0.f;

  for (int kc = 0; kc < 8; kc++){
    float4 xv = {0.f,0.f,0.f,0.f};
    if (rok) xv = *(const float4*)(xrow + kc*16);
    __syncthreads();
    *(float4*)(xs + lr*20 + lq*4) = xv;
    __syncthreads();
#pragma unroll
    for (int kk = 0; kk < 16; kk++){
      const int k = kc*16 + kk;
      float4 wv = *(const float4*)(Ws + k*64 + ct*4);
      float x0 = xs[(rt*4+0)*20 + kk];
      float x1 = xs[(rt*4+1)*20 + kk];
      float x2 = xs[(rt*4+2)*20 + kk];
      float x3 = xs[(rt*4+3)*20 + kk];
      acc[0][0] += x0*wv.x; acc[0][1] += x0*wv.y; acc[0][2] += x0*wv.z; acc[0][3] += x0*wv.w;
      acc[1][0] += x1*wv.x; acc[1][1] += x1*wv.y; acc[1][2] += x1*wv.z; acc[1][3] += x1*wv.w;
      acc[2][0] += x2*wv.x; acc[2][1] += x2*wv.y; acc[2][2] += x2*wv.z; acc[2][3] += x2*wv.w;
      acc[3][0] += x3*wv.x; acc[3][1] += x3*wv.y; acc[3][2] += x3*wv.z; acc[3][3] += x3*wv.w;
    }
  }
  const int h = ct >> 2;
  const float4 asv = *(const float4*)(a_src + ct*4);
  const float4 adv = *(const float4*)(a_dst + ct*4);
#pragma unroll
  for (int i = 0; i < 4; i++){
    int n = n0 + rt*4 + i;
    float ss = acc[i][0]*asv.x + acc[i][1]*asv.y + acc[i][2]*asv.z + acc[i][3]*asv.w;
    float dd = acc[i][0]*adv.x + acc[i][1]*adv.y + acc[i][2]*adv.z + acc[i][3]*adv.w;
    ss += __shfl_xor(ss, 1); ss += __shfl_xor(ss, 2);
    dd += __shfl_xor(dd, 1); dd += __shfl_xor(dd, 2);
    if (n < N){
      h1b[(size_t)n*32 + ct*2 + 0] = bf2(acc[i][0], acc[i][1]);
      h1b[(size_t)n*32 + ct*2 + 1] = bf2(acc[i][2], acc[i][3]);
      if ((ct & 3) == 0){
        as1[(size_t)n*4 + h] = ss;
        ad1[(size_t)n*4 + h] = dd;
      }
    }
  }
}

// ------- bucket fill: XCD-binned, 4 edges/thread/iter (4 atomic chains in flight) -------
__global__ __launch_bounds__(256) void k_fill(const int* __restrict__ ei,
                                              int* __restrict__ cnt,
                                              int* __restrict__ slots,
                                              int E, int T, int N){
  const int xcd  = blockIdx.x & 7;
  const int grp  = blockIdx.x >> 3;
  const int ngrp = gridDim.x >> 3;
  const int lo = (int)(((long long)N * xcd) >> 3);
  const int hi = (int)(((long long)N * (xcd+1)) >> 3);
  const int stride = ngrp * 256 * 4;
  for (int base = (grp*256 + (int)threadIdx.x)*4; base < T; base += stride){
    int d[4], srcv[4];
    bool act[4];
    if (base + 4 <= E && ((E + base) & 3) == 0){
      int4 dv = *(const int4*)(ei + (size_t)E + base);
      d[0]=dv.x; d[1]=dv.y; d[2]=dv.z; d[3]=dv.w;
#pragma unroll
      for (int j = 0; j < 4; j++){
        act[j] = (d[j] >= lo && d[j] < hi);
        if (act[j]) srcv[j] = ei[base+j];
      }
    } else {
#pragma unroll
      for (int j = 0; j < 4; j++){
        int i = base + j;
        if (i < T){
          int dd = (i < E) ? ei[(size_t)E+i] : (i - E);
          d[j] = dd; act[j] = (dd >= lo && dd < hi);
          if (act[j]) srcv[j] = (i < E) ? ei[i] : dd;
        } else { act[j] = false; d[j] = 0; }
      }
    }
#pragma unroll
    for (int j = 0; j < 4; j++){
      if (act[j]){
        int pos = atomicAdd(cnt + d[j], 1);
        if (pos < 64) slots[(size_t)d[j]*64 + pos] = srcv[j];
      }
    }
  }
}

// ------- layer 1: 16 edges/iter; lane=(e16,c4), lane owns head c4's 16 ch -------
__global__ __launch_bounds__(256) void k_edge1(const int* __restrict__ cnt,
     const int* __restrict__ slots, const float* __restrict__ as1,
     const float* __restrict__ ad1, const unsigned* __restrict__ h1b,
     const float* __restrict__ b1, float* __restrict__ g1, int N){
  int wave = (blockIdx.x << 2) + (threadIdx.x >> 6);
  if (wave >= N) return;
  const int lane = threadIdx.x & 63;
  const int e16 = lane >> 2;
  const int c4  = lane & 3;
  const int deg = min(cnt[wave], 64);
  const int base = wave << 6;
  const float adh = ad1[(size_t)wave*4 + c4];

  float acc[16];
#pragma unroll
  for (int i = 0; i < 16; i++) acc[i] = 0.f;
  float lsum = 0.f;

  for (int jb = 0; jb < deg; jb += 16){
    int slot = jb + e16;
    int s = 0; float p = 0.f;
    if (slot < deg){
      s = slots[base + slot];
      p = __expf(leaky(as1[(size_t)s*4 + c4] + adh));
    }
    const uint4* hp = (const uint4*)(h1b + (size_t)s*32 + c4*8);
    uint4 w0 = hp[0], w1 = hp[1];
    acc[ 0]+=p*bflo(w0.x); acc[ 1]+=p*bfhi(w0.x);
    acc[ 2]+=p*bflo(w0.y); acc[ 3]+=p*bfhi(w0.y);
    acc[ 4]+=p*bflo(w0.z); acc[ 5]+=p*bfhi(w0.z);
    acc[ 6]+=p*bflo(w0.w); acc[ 7]+=p*bfhi(w0.w);
    acc[ 8]+=p*bflo(w1.x); acc[ 9]+=p*bfhi(w1.x);
    acc[10]+=p*bflo(w1.y); acc[11]+=p*bfhi(w1.y);
    acc[12]+=p*bflo(w1.z); acc[13]+=p*bfhi(w1.z);
    acc[14]+=p*bflo(w1.w); acc[15]+=p*bfhi(w1.w);
    lsum += p;
  }
  // reduce over edge axis (lane bits 2..5)
#pragma unroll
  for (int off = 4; off < 64; off <<= 1){
#pragma unroll
    for (int i = 0; i < 16; i++) acc[i] += __shfl_xor(acc[i], off);
    lsum += __shfl_xor(lsum, off);
  }
  if (e16 == 0){
    float inv = 1.f / (lsum + GAT_EPS);
    float* gp = g1 + (size_t)wave*64 + c4*16;
    const float* bp = b1 + c4*16;
    float v[16];
#pragma unroll
    for (int i = 0; i < 16; i++){
      float u = acc[i]*inv + bp[i];
      v[i] = u > 0.f ? u : (__expf(u) - 1.f);    // ELU fused
    }
#pragma unroll
    for (int q = 0; q < 4; q++){
      float4 f; f.x=v[q*4]; f.y=v[q*4+1]; f.z=v[q*4+2]; f.w=v[q*4+3];
      *(float4*)(gp + q*4) = f;
    }
  }
}

// ------- GEMM2 + fused alpha2: h2p = padded 96B bf16 rows (24 uints) -------
__global__ __launch_bounds__(256) void k_gemm2(const float* __restrict__ g1,
                                               const float* __restrict__ W2,
                                               const float* __restrict__ a_src,
                                               const float* __restrict__ a_dst,
                                               unsigned* __restrict__ h2p,
                                               float* __restrict__ as2,
                                               float* __restrict__ ad2, int N){
  __shared__ float Ws[64*40];
  __shared__ float xs[32*64];
  const int t = threadIdx.x;
  const int n0 = blockIdx.x * 32;
  for (int i = t; i < 64*40; i += 256) Ws[i] = W2[i];
  for (int i = t; i < 32*64; i += 256){
    int n = n0 + (i >> 6);
    xs[i] = (n < N) ? g1[(size_t)n*64 + (i & 63)] : 0.f;
  }
  __syncthreads();
  const int c  = t & 63;
  const int ng = t >> 6;
  const bool act = (c < 40);
  float acc[8] = {0,0,0,0,0,0,0,0};
  if (act){
    for (int k = 0; k < 64; k++){
      float w = Ws[k*40 + c];
#pragma unroll
      for (int r = 0; r < 8; r++) acc[r] += xs[(ng*8+r)*64 + k] * w;
    }
  }
  const float av = act ? a_src[c] : 0.f;
  const float bv = act ? a_dst[c] : 0.f;
#pragma unroll
  for (int r = 0; r < 8; r++){
    int n = n0 + ng*8 + r;
    float po = __shfl_xor(acc[r], 1);
    if ((c & 1) == 0 && act && n < N)
      h2p[(size_t)n*24 + (c >> 1)] = bf2(acc[r], po);
    float ss = acc[r]*av, dd = acc[r]*bv;
#pragma unroll
    for (int off = 1; off < 64; off <<= 1){
      ss += __shfl_xor(ss, off);
      dd += __shfl_xor(dd, off);
    }
    if (c == 0 && n < N){ as2[n] = ss; ad2[n] = dd; }
  }
}

// ------- layer 2: 16 edges/iter; lane=(e16,c4), lane owns 12 ch (3x uint2) -------
__global__ __launch_bounds__(256) void k_edge2(const int* __restrict__ cnt,
     const int* __restrict__ slots, const float* __restrict__ as2,
     const float* __restrict__ ad2, const unsigned* __restrict__ h2p,
     const float* __restrict__ b2, float* __restrict__ out, int N){
  int wave = (blockIdx.x << 2) + (threadIdx.x >> 6);
  if (wave >= N) return;
  const int lane = threadIdx.x & 63;
  const int e16 = lane >> 2;
  const int c4  = lane & 3;
  const int deg = min(cnt[wave], 64);
  const int base = wave << 6;
  const float adw = ad2[wave];

  float acc[12];
#pragma unroll
  for (int i = 0; i < 12; i++) acc[i] = 0.f;
  float lsum = 0.f;

  for (int jb = 0; jb < deg; jb += 16){
    int slot = jb + e16;
    int s = 0; float p = 0.f;
    if (slot < deg){
      s = slots[base + slot];
      p = __expf(leaky(as2[s] + adw));
    }
    const uint2* hp = (const uint2*)(h2p + (size_t)s*24 + c4*6);
    uint2 w0 = hp[0], w1 = hp[1], w2 = hp[2];
    acc[ 0]+=p*bflo(w0.x); acc[ 1]+=p*bfhi(w0.x);
    acc[ 2]+=p*bflo(w0.y); acc[ 3]+=p*bfhi(w0.y);
    acc[ 4]+=p*bflo(w1.x); acc[ 5]+=p*bfhi(w1.x);
    acc[ 6]+=p*bflo(w1.y); acc[ 7]+=p*bfhi(w1.y);
    acc[ 8]+=p*bflo(w2.x); acc[ 9]+=p*bfhi(w2.x);
    acc[10]+=p*bflo(w2.y); acc[11]+=p*bfhi(w2.y);
    lsum += p;
  }
#pragma unroll
  for (int off = 4; off < 64; off <<= 1){
#pragma unroll
    for (int i = 0; i < 12; i++) acc[i] += __shfl_xor(acc[i], off);
    lsum += __shfl_xor(lsum, off);
  }
  if (e16 == 0){
    float inv = 1.f / (lsum + GAT_EPS);
    const int cbase = c4*12;
    const int nch = (c4 < 3) ? 12 : 4;        // 40 = 12+12+12+4
    float v[12];
#pragma unroll
    for (int i = 0; i < 12; i++) v[i] = acc[i]*inv;
    float* op = out + (size_t)wave*40 + cbase;
#pragma unroll
    for (int q = 0; q < 3; q++){
      if (q*4 < nch){
        float4 f;
        f.x = v[q*4+0] + b2[cbase+q*4+0];
        f.y = v[q*4+1] + b2[cbase+q*4+1];
        f.z = v[q*4+2] + b2[cbase+q*4+2];
        f.w = v[q*4+3] + b2[cbase+q*4+3];
        *(float4*)(op + q*4) = f;
      }
    }
  }
}

extern "C" void kernel_launch(void* const* d_in, const int* in_sizes, int n_in,
                              void* d_out, int out_size, void* d_ws, size_t ws_size,
                              hipStream_t stream){
  const float* x    = (const float*)d_in[0];
  const int*   ei   = (const int*)d_in[1];
  const float* W1   = (const float*)d_in[2];
  const float* a_s1 = (const float*)d_in[3];
  const float* a_d1 = (const float*)d_in[4];
  const float* b1   = (const float*)d_in[5];
  const float* W2   = (const float*)d_in[6];
  const float* a_s2 = (const float*)d_in[7];
  const float* a_d2 = (const float*)d_in[8];
  const float* b2   = (const float*)d_in[9];
  float* out = (float*)d_out;

  const int N = in_sizes[0] / 128;
  const int E = in_sizes[1] / 2;
  const int T = E + N;

  float* ws = (float*)d_ws;
  unsigned* h1b = (unsigned*)ws;  ws += (size_t)N*32;  // bf16 h1 [N][64]
  unsigned* h2p = (unsigned*)ws;  ws += (size_t)N*24;  // bf16 h2 padded 96B rows
  float* as1 = ws;  ws += (size_t)N*4;
  float* ad1 = ws;  ws += (size_t)N*4;
  float* g1  = ws;  ws += (size_t)N*64;
  float* as2 = ws;  ws += (size_t)N;
  float* ad2 = ws;  ws += (size_t)N;
  int* cnt   = (int*)ws;          ws += (size_t)N;
  int* slots = (int*)ws;          ws += (size_t)N*64;

  // bucket build (shared by both layers)
  hipMemsetAsync(cnt, 0, (size_t)N*sizeof(int), stream);
  hipLaunchKernelGGL(k_fill, dim3(2048), dim3(256), 0, stream, ei, cnt, slots, E, T, N);

  // layer 1
  hipLaunchKernelGGL(k_gemm1, dim3((N+63)/64), dim3(256), 0, stream,
                     x, W1, a_s1, a_d1, h1b, as1, ad1, N);
  hipLaunchKernelGGL(k_edge1, dim3((N+3)/4), dim3(256), 0, stream,
                     cnt, slots, as1, ad1, h1b, b1, g1, N);

  // layer 2
  hipLaunchKernelGGL(k_gemm2, dim3((N+31)/32), dim3(256), 0, stream,
                     g1, W2, a_s2, a_d2, h2p, as2, ad2, N);
  hipLaunchKernelGGL(k_edge2, dim3((N+3)/4), dim3(256), 0, stream,
                     cnt, slots, as2, ad2, h2p, b2, out, N);
}

// Round 12
// 251.012 us; speedup vs baseline: 1.0074x; 1.0074x over previous
//
#include <hip/hip_runtime.h>

#define NEG_SLOPE 0.2f
#define GAT_EPS 1e-16f

__device__ __forceinline__ float leaky(float e){ return e > 0.f ? e : NEG_SLOPE * e; }

// pack two fp32 into bf16x2 (round-to-nearest-even), low = a, high = b
__device__ __forceinline__ unsigned bf2(float a, float b){
  unsigned ua = __float_as_uint(a); ua += 0x7FFFu + ((ua >> 16) & 1u);
  unsigned ub = __float_as_uint(b); ub += 0x7FFFu + ((ub >> 16) & 1u);
  return (ua >> 16) | (ub & 0xFFFF0000u);
}
__device__ __forceinline__ float bflo(unsigned v){ return __uint_as_float(v << 16); }
__device__ __forceinline__ float bfhi(unsigned v){ return __uint_as_float(v & 0xFFFF0000u); }

// ------- GEMM1: 64x64 tile, 4x4 register blocking; bf16 h1 + alpha dots -------
__global__ __launch_bounds__(256) void k_gemm1(const float* __restrict__ x,
                                               const float* __restrict__ W,
                                               const float* __restrict__ a_src,
                                               const float* __restrict__ a_dst,
                                               unsigned* __restrict__ h1b,
                                               float* __restrict__ as1,
                                               float* __restrict__ ad1, int N){
  __shared__ float Ws[128*64];   // [k][c], 32 KB
  __shared__ float xs[64*20];    // [row][k-chunk16] pad->20, 5 KB
  const int t = threadIdx.x;
  const int n0 = blockIdx.x * 64;
  for (int i = t; i < 128*64/4; i += 256) ((float4*)Ws)[i] = ((const float4*)W)[i];
  const int ct = t & 15;
  const int rt = t >> 4;
  const int lr = t >> 2;
  const int lq = t & 3;
  const bool rok = (n0 + lr) < N;
  const float* xrow = x + (size_t)(n0 + lr)*128 + lq*4;
  float acc[4][4];
#pragma unroll
  for (int i = 0; i < 4; i++)
#pragma unroll
    for (int j = 0; j < 4; j++) acc[i][j] = 0.f;

  for (int kc = 0; kc < 8; kc++){
    float4 xv = {0.f,0.f,0.f,0.f};
    if (rok) xv = *(const float4*)(xrow + kc*16);
    __syncthreads();
    *(float4*)(xs + lr*20 + lq*4) = xv;
    __syncthreads();
#pragma unroll
    for (int kk = 0; kk < 16; kk++){
      const int k = kc*16 + kk;
      float4 wv = *(const float4*)(Ws + k*64 + ct*4);
      float x0 = xs[(rt*4+0)*20 + kk];
      float x1 = xs[(rt*4+1)*20 + kk];
      float x2 = xs[(rt*4+2)*20 + kk];
      float x3 = xs[(rt*4+3)*20 + kk];
      acc[0][0] += x0*wv.x; acc[0][1] += x0*wv.y; acc[0][2] += x0*wv.z; acc[0][3] += x0*wv.w;
      acc[1][0] += x1*wv.x; acc[1][1] += x1*wv.y; acc[1][2] += x1*wv.z; acc[1][3] += x1*wv.w;
      acc[2][0] += x2*wv.x; acc[2][1] += x2*wv.y; acc[2][2] += x2*wv.z; acc[2][3] += x2*wv.w;
      acc[3][0] += x3*wv.x; acc[3][1] += x3*wv.y; acc[3][2] += x3*wv.z; acc[3][3] += x3*wv.w;
    }
  }
  const int h = ct >> 2;
  const float4 asv = *(const float4*)(a_src + ct*4);
  const float4 adv = *(const float4*)(a_dst + ct*4);
#pragma unroll
  for (int i = 0; i < 4; i++){
    int n = n0 + rt*4 + i;
    float ss = acc[i][0]*asv.x + acc[i][1]*asv.y + acc[i][2]*asv.z + acc[i][3]*asv.w;
    float dd = acc[i][0]*adv.x + acc[i][1]*adv.y + acc[i][2]*adv.z + acc[i][3]*adv.w;
    ss += __shfl_xor(ss, 1); ss += __shfl_xor(ss, 2);
    dd += __shfl_xor(dd, 1); dd += __shfl_xor(dd, 2);
    if (n < N){
      h1b[(size_t)n*32 + ct*2 + 0] = bf2(acc[i][0], acc[i][1]);
      h1b[(size_t)n*32 + ct*2 + 1] = bf2(acc[i][2], acc[i][3]);
      if ((ct & 3) == 0){
        as1[(size_t)n*4 + h] = ss;
        ad1[(size_t)n*4 + h] = dd;
      }
    }
  }
}

// ------- bucket fill: XCD-binned; nt loads on the ei stream so the slot/cnt
// windows stay L2-resident (kills the 7x partial-line writeback amplification) -------
__global__ __launch_bounds__(256) void k_fill(const int* __restrict__ ei,
                                              int* __restrict__ cnt,
                                              int* __restrict__ slots,
                                              int E, int T, int N){
  const int xcd  = blockIdx.x & 7;
  const int grp  = blockIdx.x >> 3;
  const int ngrp = gridDim.x >> 3;
  const int lo = (int)(((long long)N * xcd) >> 3);
  const int hi = (int)(((long long)N * (xcd+1)) >> 3);
  for (int i = grp*256 + (int)threadIdx.x; i < T; i += ngrp*256){
    int dst = (i < E) ? __builtin_nontemporal_load(ei + (size_t)E + i) : (i - E);
    if (dst >= lo && dst < hi){
      int src = (i < E) ? __builtin_nontemporal_load(ei + i) : dst;
      int pos = atomicAdd(cnt + dst, 1);
      if (pos < 64) slots[(size_t)dst*64 + pos] = src;
    }
  }
}

// ------- layer 1: 16 edges/iter; lane=(e16,c4), lane owns head c4's 16 ch -------
__global__ __launch_bounds__(256) void k_edge1(const int* __restrict__ cnt,
     const int* __restrict__ slots, const float* __restrict__ as1,
     const float* __restrict__ ad1, const unsigned* __restrict__ h1b,
     const float* __restrict__ b1, float* __restrict__ g1, int N){
  int wave = (blockIdx.x << 2) + (threadIdx.x >> 6);
  if (wave >= N) return;
  const int lane = threadIdx.x & 63;
  const int e16 = lane >> 2;
  const int c4  = lane & 3;
  const int deg = min(cnt[wave], 64);
  const int base = wave << 6;
  const float adh = ad1[(size_t)wave*4 + c4];

  float acc[16];
#pragma unroll
  for (int i = 0; i < 16; i++) acc[i] = 0.f;
  float lsum = 0.f;

  for (int jb = 0; jb < deg; jb += 16){
    int slot = jb + e16;
    int s = 0; float p = 0.f;
    if (slot < deg){
      s = slots[base + slot];
      p = __expf(leaky(as1[(size_t)s*4 + c4] + adh));
    }
    const uint4* hp = (const uint4*)(h1b + (size_t)s*32 + c4*8);
    uint4 w0 = hp[0], w1 = hp[1];
    acc[ 0]+=p*bflo(w0.x); acc[ 1]+=p*bfhi(w0.x);
    acc[ 2]+=p*bflo(w0.y); acc[ 3]+=p*bfhi(w0.y);
    acc[ 4]+=p*bflo(w0.z); acc[ 5]+=p*bfhi(w0.z);
    acc[ 6]+=p*bflo(w0.w); acc[ 7]+=p*bfhi(w0.w);
    acc[ 8]+=p*bflo(w1.x); acc[ 9]+=p*bfhi(w1.x);
    acc[10]+=p*bflo(w1.y); acc[11]+=p*bfhi(w1.y);
    acc[12]+=p*bflo(w1.z); acc[13]+=p*bfhi(w1.z);
    acc[14]+=p*bflo(w1.w); acc[15]+=p*bfhi(w1.w);
    lsum += p;
  }
  // reduce over edge axis (lane bits 2..5)
#pragma unroll
  for (int off = 4; off < 64; off <<= 1){
#pragma unroll
    for (int i = 0; i < 16; i++) acc[i] += __shfl_xor(acc[i], off);
    lsum += __shfl_xor(lsum, off);
  }
  if (e16 == 0){
    float inv = 1.f / (lsum + GAT_EPS);
    float* gp = g1 + (size_t)wave*64 + c4*16;
    const float* bp = b1 + c4*16;
    float v[16];
#pragma unroll
    for (int i = 0; i < 16; i++){
      float u = acc[i]*inv + bp[i];
      v[i] = u > 0.f ? u : (__expf(u) - 1.f);    // ELU fused
    }
#pragma unroll
    for (int q = 0; q < 4; q++){
      float4 f; f.x=v[q*4]; f.y=v[q*4+1]; f.z=v[q*4+2]; f.w=v[q*4+3];
      *(float4*)(gp + q*4) = f;
    }
  }
}

// ------- GEMM2 + fused alpha2: h2p = padded 96B bf16 rows (24 uints) -------
__global__ __launch_bounds__(256) void k_gemm2(const float* __restrict__ g1,
                                               const float* __restrict__ W2,
                                               const float* __restrict__ a_src,
                                               const float* __restrict__ a_dst,
                                               unsigned* __restrict__ h2p,
                                               float* __restrict__ as2,
                                               float* __restrict__ ad2, int N){
  __shared__ float Ws[64*40];
  __shared__ float xs[32*64];
  const int t = threadIdx.x;
  const int n0 = blockIdx.x * 32;
  for (int i = t; i < 64*40; i += 256) Ws[i] = W2[i];
  for (int i = t; i < 32*64; i += 256){
    int n = n0 + (i >> 6);
    xs[i] = (n < N) ? g1[(size_t)n*64 + (i & 63)] : 0.f;
  }
  __syncthreads();
  const int c  = t & 63;
  const int ng = t >> 6;
  const bool act = (c < 40);
  float acc[8] = {0,0,0,0,0,0,0,0};
  if (act){
    for (int k = 0; k < 64; k++){
      float w = Ws[k*40 + c];
#pragma unroll
      for (int r = 0; r < 8; r++) acc[r] += xs[(ng*8+r)*64 + k] * w;
    }
  }
  const float av = act ? a_src[c] : 0.f;
  const float bv = act ? a_dst[c] : 0.f;
#pragma unroll
  for (int r = 0; r < 8; r++){
    int n = n0 + ng*8 + r;
    float po = __shfl_xor(acc[r], 1);
    if ((c & 1) == 0 && act && n < N)
      h2p[(size_t)n*24 + (c >> 1)] = bf2(acc[r], po);
    float ss = acc[r]*av, dd = acc[r]*bv;
#pragma unroll
    for (int off = 1; off < 64; off <<= 1){
      ss += __shfl_xor(ss, off);
      dd += __shfl_xor(dd, off);
    }
    if (c == 0 && n < N){ as2[n] = ss; ad2[n] = dd; }
  }
}

// ------- layer 2: 16 edges/iter; lane=(e16,c4), lane owns 12 ch (3x uint2) -------
__global__ __launch_bounds__(256) void k_edge2(const int* __restrict__ cnt,
     const int* __restrict__ slots, const float* __restrict__ as2,
     const float* __restrict__ ad2, const unsigned* __restrict__ h2p,
     const float* __restrict__ b2, float* __restrict__ out, int N){
  int wave = (blockIdx.x << 2) + (threadIdx.x >> 6);
  if (wave >= N) return;
  const int lane = threadIdx.x & 63;
  const int e16 = lane >> 2;
  const int c4  = lane & 3;
  const int deg = min(cnt[wave], 64);
  const int base = wave << 6;
  const float adw = ad2[wave];

  float acc[12];
#pragma unroll
  for (int i = 0; i < 12; i++) acc[i] = 0.f;
  float lsum = 0.f;

  for (int jb = 0; jb < deg; jb += 16){
    int slot = jb + e16;
    int s = 0; float p = 0.f;
    if (slot < deg){
      s = slots[base + slot];
      p = __expf(leaky(as2[s] + adw));
    }
    const uint2* hp = (const uint2*)(h2p + (size_t)s*24 + c4*6);
    uint2 w0 = hp[0], w1 = hp[1], w2 = hp[2];
    acc[ 0]+=p*bflo(w0.x); acc[ 1]+=p*bfhi(w0.x);
    acc[ 2]+=p*bflo(w0.y); acc[ 3]+=p*bfhi(w0.y);
    acc[ 4]+=p*bflo(w1.x); acc[ 5]+=p*bfhi(w1.x);
    acc[ 6]+=p*bflo(w1.y); acc[ 7]+=p*bfhi(w1.y);
    acc[ 8]+=p*bflo(w2.x); acc[ 9]+=p*bfhi(w2.x);
    acc[10]+=p*bflo(w2.y); acc[11]+=p*bfhi(w2.y);
    lsum += p;
  }
#pragma unroll
  for (int off = 4; off < 64; off <<= 1){
#pragma unroll
    for (int i = 0; i < 12; i++) acc[i] += __shfl_xor(acc[i], off);
    lsum += __shfl_xor(lsum, off);
  }
  if (e16 == 0){
    float inv = 1.f / (lsum + GAT_EPS);
    const int cbase = c4*12;
    const int nch = (c4 < 3) ? 12 : 4;        // 40 = 12+12+12+4
    float v[12];
#pragma unroll
    for (int i = 0; i < 12; i++) v[i] = acc[i]*inv;
    float* op = out + (size_t)wave*40 + cbase;
#pragma unroll
    for (int q = 0; q < 3; q++){
      if (q*4 < nch){
        float4 f;
        f.x = v[q*4+0] + b2[cbase+q*4+0];
        f.y = v[q*4+1] + b2[cbase+q*4+1];
        f.z = v[q*4+2] + b2[cbase+q*4+2];
        f.w = v[q*4+3] + b2[cbase+q*4+3];
        *(float4*)(op + q*4) = f;
      }
    }
  }
}

extern "C" void kernel_launch(void* const* d_in, const int* in_sizes, int n_in,
                              void* d_out, int out_size, void* d_ws, size_t ws_size,
                              hipStream_t stream){
  const float* x    = (const float*)d_in[0];
  const int*   ei   = (const int*)d_in[1];
  const float* W1   = (const float*)d_in[2];
  const float* a_s1 = (const float*)d_in[3];
  const float* a_d1 = (const float*)d_in[4];
  const float* b1   = (const float*)d_in[5];
  const float* W2   = (const float*)d_in[6];
  const float* a_s2 = (const float*)d_in[7];
  const float* a_d2 = (const float*)d_in[8];
  const float* b2   = (const float*)d_in[9];
  float* out = (float*)d_out;

  const int N = in_sizes[0] / 128;
  const int E = in_sizes[1] / 2;
  const int T = E + N;

  float* ws = (float*)d_ws;
  unsigned* h1b = (unsigned*)ws;  ws += (size_t)N*32;  // bf16 h1 [N][64]
  unsigned* h2p = (unsigned*)ws;  ws += (size_t)N*24;  // bf16 h2 padded 96B rows
  float* as1 = ws;  ws += (size_t)N*4;
  float* ad1 = ws;  ws += (size_t)N*4;
  float* g1  = ws;  ws += (size_t)N*64;
  float* as2 = ws;  ws += (size_t)N;
  float* ad2 = ws;  ws += (size_t)N;
  int* cnt   = (int*)ws;          ws += (size_t)N;
  int* slots = (int*)ws;          ws += (size_t)N*64;

  // bucket build (shared by both layers)
  hipMemsetAsync(cnt, 0, (size_t)N*sizeof(int), stream);
  hipLaunchKernelGGL(k_fill, dim3(2048), dim3(256), 0, stream, ei, cnt, slots, E, T, N);

  // layer 1
  hipLaunchKernelGGL(k_gemm1, dim3((N+63)/64), dim3(256), 0, stream,
                     x, W1, a_s1, a_d1, h1b, as1, ad1, N);
  hipLaunchKernelGGL(k_edge1, dim3((N+3)/4), dim3(256), 0, stream,
                     cnt, slots, as1, ad1, h1b, b1, g1, N);

  // layer 2
  hipLaunchKernelGGL(k_gemm2, dim3((N+31)/32), dim3(256), 0, stream,
                     g1, W2, a_s2, a_d2, h2p, as2, ad2, N);
  hipLaunchKernelGGL(k_edge2, dim3((N+3)/4), dim3(256), 0, stream,
                     cnt, slots, as2, ad2, h2p, b2, out, N);
}